// Round 3
// baseline (7040.116 us; speedup 1.0000x reference)
//
#include <hip/hip_runtime.h>
#include <hip/hip_bf16.h>

#define B_ 16
#define T_ 32
#define S_ 256
#define K_ 8
#define L_ 64
#define V_ 32000
#define VX_ 32050
#define NEG_ -1e10f
#define NBLK_ 256

__device__ __forceinline__ float fsigmoid(float x){ return 1.f/(1.f+__expf(-x)); }
__device__ __forceinline__ float ftanh(float x){ float e=__expf(2.f*x); return 1.f - 2.f/(e+1.f); }

// ---- software grid barrier (plain launch, graph-capture safe) ----
__device__ __forceinline__ void gridbar(unsigned* cnt, unsigned* gen){
  __syncthreads();
  if (threadIdx.x == 0){
    __threadfence();
    unsigned g = __hip_atomic_load(gen, __ATOMIC_RELAXED, __HIP_MEMORY_SCOPE_AGENT);
    unsigned a = __hip_atomic_fetch_add(cnt, 1u, __ATOMIC_ACQ_REL, __HIP_MEMORY_SCOPE_AGENT);
    if (a == NBLK_-1u){
      __hip_atomic_store(cnt, 0u, __ATOMIC_RELAXED, __HIP_MEMORY_SCOPE_AGENT);
      __hip_atomic_store(gen, g+1u, __ATOMIC_RELEASE, __HIP_MEMORY_SCOPE_AGENT);
    } else {
      while (__hip_atomic_load(gen, __ATOMIC_ACQUIRE, __HIP_MEMORY_SCOPE_AGENT) == g){
        __builtin_amdgcn_s_sleep(2);
      }
    }
    __threadfence();
  }
  __syncthreads();
}

// ---------------- embed fill: X[t][b][0:512] = embedding[tgt[b][t]] ----------------
__global__ void k_embed(const float* __restrict__ emb, const int* __restrict__ tgt, float* __restrict__ X){
  int idx = blockIdx.x*256 + threadIdx.x;
  if (idx >= T_*B_*512) return;
  int t = idx >> 13; int b = (idx >> 9) & 15; int e = idx & 511;
  int tok = tgt[b*T_ + t];
  X[(size_t)(t*B_+b)*1536 + e] = emb[(size_t)tok*512 + e];
}

// ---------------- generic f32 GEMM: C[M,N] = A[M,K](ldA) * W[N,K](ldW)^T + bias ----------------
template<bool PERM>
__global__ __launch_bounds__(256) void k_gemm(const float* __restrict__ A, int ldA,
    const float* __restrict__ W, int ldW,
    const float* __restrict__ bias, float* __restrict__ C, int K, int ldC){
  __shared__ float As[16][132];
  __shared__ float Ws[16][68];
  const int m0 = blockIdx.x*128, n0 = blockIdx.y*64;
  const int tid = threadIdx.x;
  const int tm = tid & 15, tn = tid >> 4;
  float acc[8][4];
#pragma unroll
  for (int i=0;i<8;++i)
#pragma unroll
    for(int j=0;j<4;++j) acc[i][j]=0.f;
  for (int k0=0;k0<K;k0+=16){
#pragma unroll
    for (int rr=0;rr<2;++rr){
      int f = tid + rr*256;
      int mm = f >> 2, kc = f & 3;
      const float4 v = *(const float4*)(A + (size_t)(m0+mm)*ldA + k0 + kc*4);
      As[kc*4+0][mm]=v.x; As[kc*4+1][mm]=v.y; As[kc*4+2][mm]=v.z; As[kc*4+3][mm]=v.w;
    }
    {
      int nn = tid >> 2, kc = tid & 3;
      const float4 v = *(const float4*)(W + (size_t)(n0+nn)*ldW + k0 + kc*4);
      Ws[kc*4+0][nn]=v.x; Ws[kc*4+1][nn]=v.y; Ws[kc*4+2][nn]=v.z; Ws[kc*4+3][nn]=v.w;
    }
    __syncthreads();
#pragma unroll
    for (int kk=0;kk<16;++kk){
      float a[8], w[4];
      float4 a0 = *(const float4*)&As[kk][tm*8];
      float4 a1 = *(const float4*)&As[kk][tm*8+4];
      float4 w0 = *(const float4*)&Ws[kk][tn*4];
      a[0]=a0.x;a[1]=a0.y;a[2]=a0.z;a[3]=a0.w;a[4]=a1.x;a[5]=a1.y;a[6]=a1.z;a[7]=a1.w;
      w[0]=w0.x;w[1]=w0.y;w[2]=w0.z;w[3]=w0.w;
#pragma unroll
      for (int i=0;i<8;++i)
#pragma unroll
        for (int j=0;j<4;++j) acc[i][j] += a[i]*w[j];
    }
    __syncthreads();
  }
#pragma unroll
  for (int i=0;i<8;++i){
    int m = m0 + tm*8 + i;
    size_t row = PERM ? (size_t)((m&15)*T_ + (m>>4)) : (size_t)m;
#pragma unroll
    for (int j=0;j<4;++j){
      int n = n0 + tn*4 + j;
      C[row*(size_t)ldC + n] = acc[i][j] + (bias ? bias[n] : 0.f);
    }
  }
}

// ---------------- persistent recurrence kernel (plain launch + software barrier) ----------------
struct RP {
  const float *inith, *src, *smask, *kgh, *kmask;
  const float *Wq_c, *Wq_k, *Vw_c, *bV_c, *Vw_k, *bV_k;
  const float *W_ih, *W_hh, *b_ih, *b_hh;
  const float *PVS, *PVK, *GIY;
  float *Xb, *S_all, *KW, *HQC, *HQK, *Eg, *EKg;
  unsigned *cnt, *gen;
};

__global__ __launch_bounds__(256) void k_recur(RP p){
  const int c = blockIdx.x, tid = threadIdx.x;
  __shared__ float hS[16*513];
  __shared__ float hqbS[528], vwS[528];
  __shared__ float eS[256], wS[256], red[256], part[256];

  for (int t=0; t<T_; ++t){
    const float* h = (t==0) ? p.inith : (p.S_all + (size_t)(t-1)*B_*512);
    // stage h into LDS (padded 513)
    for (int i=tid; i<8192; i+=256) hS[(i>>9)*513 + (i&511)] = h[i];
    __syncthreads();

    // ---- Phase A: HQ = [Wq_c@h ; Wq_k@h]. block c owns j = 2c,2c+1 ----
    {
      int lane = tid & 63, combo = tid >> 6;
      int j2 = combo & 1, mat = combo >> 1;
      int j = 2*c + j2;
      int kk = lane & 3, b = lane >> 2;
      const float* wrow = (mat ? p.Wq_k : p.Wq_c) + (size_t)j*512 + kk*128;
      const float* hb = hS + b*513 + kk*128;
      float s = 0.f;
#pragma unroll 8
      for (int m=0;m<32;++m){
        float4 w = *(const float4*)(wrow + m*4);
        s += w.x*hb[m*4+0] + w.y*hb[m*4+1] + w.z*hb[m*4+2] + w.w*hb[m*4+3];
      }
      s += __shfl_down(s, 2, 64);
      s += __shfl_down(s, 1, 64);
      if ((lane & 3) == 0){
        if (mat) p.HQK[b*512 + j] = s; else p.HQC[b*512 + j] = s;
      }
    }
    gridbar(p.cnt, p.gen);

    // ---- Phase B: e_src (all blocks) + e_kg (blocks < 128) ----
    {
      int b = c >> 4;
      for (int i=tid; i<512; i+=256){
        int pos = (i>>5)*33 + (i&31);
        hqbS[pos] = p.HQC[b*512 + i];
        vwS[pos]  = p.Vw_c[i];
      }
      __syncthreads();
      int sI = (c & 15)*16 + (tid >> 4), l = tid & 15;
      const float* pv = p.PVS + ((size_t)(b*S_ + sI))*512 + l*32;
      float pvr[32];
#pragma unroll
      for (int m=0;m<8;++m){
        float4 v = *(const float4*)(pv + m*4);
        pvr[m*4]=v.x; pvr[m*4+1]=v.y; pvr[m*4+2]=v.z; pvr[m*4+3]=v.w;
      }
      float s = 0.f;
#pragma unroll
      for (int i=0;i<32;++i){
        s += ftanh(pvr[i] + hqbS[l*33+i]) * vwS[l*33+i];
      }
#pragma unroll
      for (int off=8; off>0; off>>=1) s += __shfl_down(s, off, 16);
      if (l == 0){
        float v = s + p.bV_c[0];
        if (p.smask[b*S_ + sI] == 0.f) v += NEG_;
        p.Eg[b*S_ + sI] = v;
      }
      if (c < 128 && tid < 64){
        int bb = c >> 3, kk = c & 7;
        const float* pvk = p.PVK + ((size_t)(bb*K_ + kk))*512;
        const float* hqk = p.HQK + bb*512;
        float s2 = 0.f;
#pragma unroll
        for (int m=0;m<8;++m){ int j = tid*8+m; s2 += ftanh(pvk[j] + hqk[j]) * p.Vw_k[j]; }
#pragma unroll
        for (int off=32; off>0; off>>=1) s2 += __shfl_down(s2, off, 64);
        if (tid == 0){
          float v = s2 + p.bV_k[0];
          if (p.kmask[bb*K_ + kk] == 0.f) v += NEG_;
          p.EKg[bb*K_ + kk] = v;
        }
      }
    }
    gridbar(p.cnt, p.gen);

    // ---- Phase CD: softmax + c_t, k_t, KW. block c: b = c>>4, j0 = (c&15)*32 ----
    {
      int b = c >> 4, j0 = (c & 15)*32;
      eS[tid] = p.Eg[b*S_ + tid];
      __syncthreads();
      red[tid] = eS[tid]; __syncthreads();
      for (int s=128;s>0;s>>=1){ if (tid<s) red[tid]=fmaxf(red[tid],red[tid+s]); __syncthreads(); }
      float M = red[0]; __syncthreads();
      float ex = __expf(eS[tid]-M);
      wS[tid] = ex; red[tid] = ex; __syncthreads();
      for (int s=128;s>0;s>>=1){ if (tid<s) red[tid]+=red[tid+s]; __syncthreads(); }
      float invZ = 1.f/red[0];
      wS[tid] *= invZ;
      __syncthreads();
      // c_t
      int jj = tid & 31, ss = tid >> 5;
      const float* sp = p.src + ((size_t)(b*S_ + ss*32))*512 + j0 + jj;
      float acc = 0.f;
#pragma unroll 8
      for (int i=0;i<32;++i){
        int ii = (i + 4*ss) & 31;
        acc += wS[ss*32 + ii] * sp[(size_t)ii*512];
      }
      part[tid] = acc;
      __syncthreads();
      size_t rbase = (size_t)t*16 + b;
      if (tid < 32){
        float v = 0.f;
#pragma unroll
        for (int g=0; g<8; ++g) v += part[g*32 + tid];
        p.Xb[rbase*1536 + 512 + j0 + tid] = v;
        // k_t (redundant tiny softmax over 8 kg keys)
        float ekv[8]; float mk = -1e30f;
#pragma unroll
        for (int kk=0;kk<8;++kk){ ekv[kk] = p.EKg[b*8+kk]; mk = fmaxf(mk, ekv[kk]); }
        float z = 0.f;
#pragma unroll
        for (int kk=0;kk<8;++kk){ ekv[kk] = __expf(ekv[kk]-mk); z += ekv[kk]; }
        float kt = 0.f;
#pragma unroll
        for (int kk=0;kk<8;++kk) kt += ekv[kk] * p.kgh[((size_t)(b*8+kk))*512 + j0 + tid];
        p.Xb[rbase*1536 + 1024 + j0 + tid] = kt / z;
      }
      if ((c & 15) == 0 && tid < 8){
        float mk = -1e30f;
#pragma unroll
        for (int kk=0;kk<8;++kk) mk = fmaxf(mk, p.EKg[b*8+kk]);
        float z = 0.f;
#pragma unroll
        for (int kk=0;kk<8;++kk) z += __expf(p.EKg[b*8+kk]-mk);
        p.KW[t*128 + b*8 + tid] = __expf(p.EKg[b*8+tid]-mk)/z;
      }
    }
    gridbar(p.cnt, p.gen);

    // ---- Phase E: GRU. block c owns output columns j = 2c, 2c+1 ----
    {
      int b = tid >> 4, l = tid & 15;
      size_t rbase = (size_t)t*16 + b;
      const float* xp = p.Xb + rbase*1536 + 512 + l*64;
      float xr[64];
#pragma unroll
      for (int m=0;m<16;++m){
        float4 v = *(const float4*)(xp + m*4);
        xr[m*4]=v.x; xr[m*4+1]=v.y; xr[m*4+2]=v.z; xr[m*4+3]=v.w;
      }
      float gv[6], hv6[6];
#pragma unroll
      for (int g=0; g<3; ++g){
#pragma unroll
        for (int j2=0; j2<2; ++j2){
          int row = g*512 + 2*c + j2;
          const float* wr = p.W_ih + (size_t)row*1536 + 512 + l*64;
          float s = 0.f;
#pragma unroll
          for (int m=0;m<16;++m){
            float4 w = *(const float4*)(wr + m*4);
            s += xr[m*4]*w.x + xr[m*4+1]*w.y + xr[m*4+2]*w.z + xr[m*4+3]*w.w;
          }
          const float* wh = p.W_hh + (size_t)row*512 + l*32;
          const float* hb = hS + b*513 + l*32;
          float s2 = 0.f;
#pragma unroll 8
          for (int i=0;i<32;++i){ int ii = (i + 2*l) & 31; s2 += hb[ii]*wh[ii]; }
          gv[g*2+j2] = s; hv6[g*2+j2] = s2;
        }
      }
#pragma unroll
      for (int q=0;q<6;++q){
        float a = gv[q], bb = hv6[q];
#pragma unroll
        for (int off=8; off>0; off>>=1){ a += __shfl_down(a, off, 16); bb += __shfl_down(bb, off, 16); }
        gv[q]=a; hv6[q]=bb;
      }
      if (l == 0){
#pragma unroll
        for (int j2=0;j2<2;++j2){
          int j = 2*c + j2;
          float gir = gv[0+j2] + p.GIY[rbase*1536 + j]        + p.b_ih[j];
          float giz = gv[2+j2] + p.GIY[rbase*1536 + 512 + j]  + p.b_ih[512+j];
          float gin = gv[4+j2] + p.GIY[rbase*1536 + 1024 + j] + p.b_ih[1024+j];
          float ghr = hv6[0+j2] + p.b_hh[j];
          float ghz = hv6[2+j2] + p.b_hh[512+j];
          float ghn = hv6[4+j2] + p.b_hh[1024+j];
          float rg = fsigmoid(gir + ghr);
          float zg = fsigmoid(giz + ghz);
          float ng = ftanh(gin + rg*ghn);
          float hold = hS[b*513 + j];
          p.S_all[rbase*512 + j] = (1.f - zg)*ng + zg*hold;
        }
      }
    }
    gridbar(p.cnt, p.gen);
  }
}

// ---------------- build CAT4 = [s, c, k, kf] (512 x 2048) ----------------
__global__ void k_cat4(const float* __restrict__ S_all, const float* __restrict__ X,
    const float* __restrict__ kgf, float* __restrict__ CAT){
  int idx = blockIdx.x*256 + threadIdx.x;
  if (idx >= 512*2048) return;
  int r = idx >> 11, c = idx & 2047;
  float v;
  if (c < 512) v = S_all[(size_t)r*512 + c];
  else if (c < 1536) v = X[(size_t)r*1536 + c];
  else v = kgf[(r & 15)*512 + (c - 1536)];
  CAT[idx] = v;
}

// ---------------- ptr = sigmoid([c,s,y,kf,k] . Wptr + bptr) ----------------
__global__ __launch_bounds__(256) void k_ptr(const float* __restrict__ X, const float* __restrict__ S_all,
    const float* __restrict__ kgf, const float* __restrict__ Wptr, const float* __restrict__ bptr,
    float* __restrict__ PTR){
  int r = blockIdx.x*4 + (threadIdx.x >> 6);
  int lane = threadIdx.x & 63;
  const float* seg[5];
  seg[0] = X + (size_t)r*1536 + 512;
  seg[1] = S_all + (size_t)r*512;
  seg[2] = X + (size_t)r*1536;
  seg[3] = kgf + (r & 15)*512;
  seg[4] = X + (size_t)r*1536 + 1024;
  float s = 0.f;
#pragma unroll
  for (int g=0; g<5; ++g){
    const float* p = seg[g];
    const float* w = Wptr + g*512;
#pragma unroll
    for (int m=0;m<8;++m){ int i = lane + m*64; s += p[i]*w[i]; }
  }
#pragma unroll
  for (int off=32;off>0;off>>=1) s += __shfl_down(s, off, 64);
  if (lane == 0) PTR[r] = fsigmoid(s + bptr[0]);
}

// ---------------- softmax over V, * ptr, zero extras ----------------
__global__ __launch_bounds__(256) void k_softmax(float* __restrict__ out, const float* __restrict__ PTR){
  int orow = blockIdx.x;
  int b = orow >> 5, t = orow & 31;
  int r = t*16 + b;
  float* f = out + (size_t)orow * VX_;
  __shared__ float red[256];
  int tid = threadIdx.x;
  float lm = -1e30f;
  for (int v = tid; v < V_; v += 256) lm = fmaxf(lm, f[v]);
  red[tid] = lm; __syncthreads();
  for (int s=128;s>0;s>>=1){ if (tid<s) red[tid]=fmaxf(red[tid],red[tid+s]); __syncthreads(); }
  float M = red[0]; __syncthreads();
  float ls = 0.f;
  for (int v = tid; v < V_; v += 256){ float e2 = __expf(f[v]-M); f[v] = e2; ls += e2; }
  red[tid] = ls; __syncthreads();
  for (int s=128;s>0;s>>=1){ if (tid<s) red[tid]+=red[tid+s]; __syncthreads(); }
  float scale = PTR[r] / red[0];
  for (int v = tid; v < V_; v += 256) f[v] *= scale;
  for (int v = V_ + tid; v < VX_; v += 256) f[v] = 0.f;
}

// ---------------- copy-dist + scatter ----------------
__global__ __launch_bounds__(256) void k_scatter(const float* __restrict__ Q, const float* __restrict__ kgo,
    const float* __restrict__ kpmask, const int* __restrict__ kev, const float* __restrict__ KW,
    const float* __restrict__ PTR, float* __restrict__ out){
  int bid = blockIdx.x;
  int tg = bid & 3, k = (bid >> 2) & 7, b = bid >> 5;
  int tid = threadIdx.x;
  int l = tid >> 2, qtr = tid & 3;
  __shared__ float qs[512];
  __shared__ float part[256];
  const float* kgrow = kgo + (size_t)((b*8 + k)*64 + l) * 512;
  for (int tt=0; tt<8; ++tt){
    int t = tg*8 + tt;
    int r = t*16 + b;
    int orow = b*32 + t;
    qs[tid] = Q[(size_t)r*512 + tid];
    qs[256 + tid] = Q[(size_t)r*512 + 256 + tid];
    __syncthreads();
    float p = 0.f;
    const float4* q4 = (const float4*)(qs) + qtr*32;
    const float4* k4 = (const float4*)(kgrow) + qtr*32;
#pragma unroll 4
    for (int m=0;m<32;++m){ float4 a=q4[m], c=k4[m]; p += a.x*c.x+a.y*c.y+a.z*c.z+a.w*c.w; }
    part[tid] = p;
    __syncthreads();
    if (tid < 64){
      float ev = part[tid*4]+part[tid*4+1]+part[tid*4+2]+part[tid*4+3];
      if (kpmask[(b*8+k)*64 + tid] == 0.f) ev += NEG_;
      float mx = ev;
#pragma unroll
      for (int off=32;off>0;off>>=1) mx = fmaxf(mx, __shfl_xor(mx, off, 64));
      float ex = __expf(ev - mx);
      float z = ex;
#pragma unroll
      for (int off=32;off>0;off>>=1) z += __shfl_xor(z, off, 64);
      float val = (ex/z) * KW[t*128 + b*8 + k] * (1.f - PTR[r]);
      atomicAdd(out + (size_t)orow*VX_ + kev[(b*8+k)*64 + tid], val);
    }
    __syncthreads();
  }
}

// ---------------- final normalize ----------------
__global__ __launch_bounds__(256) void k_norm(float* __restrict__ out){
  int orow = blockIdx.x;
  float* f = out + (size_t)orow*VX_;
  __shared__ float red[256];
  int tid = threadIdx.x;
  float ls = 0.f;
  for (int v=tid; v<VX_; v+=256) ls += f[v];
  red[tid]=ls; __syncthreads();
  for (int s=128;s>0;s>>=1){ if (tid<s) red[tid]+=red[tid+s]; __syncthreads(); }
  float inv = 1.f/red[0];
  for (int v=tid; v<VX_; v+=256) f[v] *= inv;
}

extern "C" void kernel_launch(void* const* d_in, const int* in_sizes, int n_in,
                              void* d_out, int out_size, void* d_ws, size_t ws_size,
                              hipStream_t stream) {
  const int*   tgt   = (const int*)  d_in[0];
  const float* inith = (const float*)d_in[1];
  const float* src   = (const float*)d_in[2];
  const float* smask = (const float*)d_in[3];
  const float* kgh   = (const float*)d_in[4];
  const float* kgf   = (const float*)d_in[5];
  const float* kgo   = (const float*)d_in[6];
  const float* kmask = (const float*)d_in[7];
  const float* kpmask= (const float*)d_in[8];
  const int*   kev   = (const int*)  d_in[10];
  const float* emb   = (const float*)d_in[12];
  const float* W_ih  = (const float*)d_in[13];
  const float* W_hh  = (const float*)d_in[14];
  const float* b_ih  = (const float*)d_in[15];
  const float* b_hh  = (const float*)d_in[16];
  const float* Wq_c  = (const float*)d_in[17];
  const float* Wv_c  = (const float*)d_in[18];
  const float* bv_c  = (const float*)d_in[19];
  const float* Vw_c  = (const float*)d_in[20];
  const float* bV_c  = (const float*)d_in[21];
  const float* Wq_k  = (const float*)d_in[22];
  const float* Wv_k  = (const float*)d_in[23];
  const float* bv_k  = (const float*)d_in[24];
  const float* Vw_k  = (const float*)d_in[25];
  const float* bV_k  = (const float*)d_in[26];
  const float* W1    = (const float*)d_in[27];
  const float* b1    = (const float*)d_in[28];
  const float* W2    = (const float*)d_in[29];
  const float* b2    = (const float*)d_in[30];
  const float* Wptr  = (const float*)d_in[31];
  const float* bptr  = (const float*)d_in[32];
  const float* Wcpy  = (const float*)d_in[33];
  const float* bcpy  = (const float*)d_in[34];
  float* out = (float*)d_out;

  float* Xb    = (float*)d_ws;            // (T,B,1536)
  float* S_all = Xb    + 786432;          // (T*B,512)
  float* PVS   = S_all + 262144;          // (B,S,512)
  float* PVK   = PVS   + 2097152;         // (B,8,512)
  float* KW    = PVK   + 65536;           // (T,B,8)
  float* GIY   = KW    + 4096;            // (512,1536)
  float* HQC   = GIY   + 786432;          // (16,512)
  float* HQK   = HQC   + 8192;            // (16,512)
  float* Eg    = HQK   + 8192;            // (16,256)
  float* EKg   = Eg    + 4096;            // (16,8)
  float* CAT   = EKg   + 128;             // (512,2048)
  float* HID   = CAT   + 1048576;         // (512,512)
  float* Qb    = HID   + 262144;          // (512,512)
  float* PTR   = Qb    + 262144;          // (512)
  unsigned* BAR = (unsigned*)(PTR + 512); // 2 words: cnt, gen

  // zero the barrier state (graph-capture legal)
  hipMemsetAsync(BAR, 0, 2*sizeof(unsigned), stream);

  // prep
  k_embed<<<(T_*B_*512+255)/256, 256, 0, stream>>>(emb, tgt, Xb);
  k_gemm<false><<<dim3(32,8), 256, 0, stream>>>(src, 512, Wv_c, 512, bv_c, PVS, 512, 512);
  k_gemm<false><<<dim3(1,8),  256, 0, stream>>>(kgh, 512, Wv_k, 512, bv_k, PVK, 512, 512);
  k_gemm<false><<<dim3(4,24), 256, 0, stream>>>(Xb, 1536, W_ih, 1536, nullptr, GIY, 512, 1536);

  // persistent recurrence (plain launch; software grid barrier inside)
  RP rp { inith, src, smask, kgh, kmask, Wq_c, Wq_k, Vw_c, bV_c, Vw_k, bV_k,
          W_ih, W_hh, b_ih, b_hh, PVS, PVK, GIY, Xb, S_all, KW, HQC, HQK, Eg, EKg,
          BAR, BAR+1 };
  k_recur<<<NBLK_, 256, 0, stream>>>(rp);

  // parallel epilogue
  k_cat4<<<(512*2048+255)/256, 256, 0, stream>>>(S_all, Xb, kgf, CAT);
  k_gemm<false><<<dim3(4,8),   256, 0, stream>>>(CAT, 2048, W1, 2048, b1, HID, 2048, 512);
  k_gemm<false><<<dim3(4,8),   256, 0, stream>>>(S_all, 512, Wcpy, 512, bcpy, Qb, 512, 512);
  k_ptr<<<128, 256, 0, stream>>>(Xb, S_all, kgf, Wptr, bptr, PTR);
  k_gemm<true><<<dim3(4,500),  256, 0, stream>>>(HID, 512, W2, 512, b2, out, 512, VX_);
  k_softmax<<<512, 256, 0, stream>>>(out, PTR);
  k_scatter<<<512, 256, 0, stream>>>(Qb, kgo, kpmask, kev, KW, PTR, out);
  k_norm<<<512, 256, 0, stream>>>(out);
}